// Round 1
// baseline (151.598 us; speedup 1.0000x reference)
//
#include <hip/hip_runtime.h>
#include <stdint.h>

#define U 128
#define V 128
#define IN_STRIDE 512
#define OUT_STRIDE 512
#define NEXP 4
#define W_STRIDE (8 * U * V) /* 131072 floats per expert */
#define B_ROWS 32768

// Workspace layout (bytes)
#define WS_WSHUF 0                         // 524288 ushorts (1 MB) shuffled bf16 weights
#define WS_PERM (1048576)                  // int[32768]
#define WS_COUNTS (1048576 + 131072)       // int[4]
#define WS_CURS (WS_COUNTS + 16)           // int[4]

typedef __bf16 bf16x8 __attribute__((ext_vector_type(8)));
typedef float f32x16 __attribute__((ext_vector_type(16)));
typedef unsigned int u32x4 __attribute__((ext_vector_type(4)));
typedef unsigned int u32x2 __attribute__((ext_vector_type(2)));

static __device__ __forceinline__ unsigned short f2bf(float f) {
    unsigned int u = __builtin_bit_cast(unsigned int, f);
    u += 0x7FFFu + ((u >> 16) & 1u);   // round-to-nearest-even
    return (unsigned short)(u >> 16);
}

// ---------------------------------------------------------------------------
// prep: blocks [0,256) shuffle weights fp32 -> bf16 in MFMA B-fragment layout
//       (layout flat index = ((((e*8+s)*4+nt)*8+kt)*64+lane)*8+j,
//        element = W[e][s][k = kt*16+(lane>>5)*8+j][n = nt*32+(lane&31)],
//        segs 4..7 pre-scaled by 0.5);
//       blocks [256,384) histogram expert ids.
// ---------------------------------------------------------------------------
__global__ void prep_kernel(const float* __restrict__ w, const int* __restrict__ wid,
                            unsigned short* __restrict__ wshuf, int* __restrict__ counts) {
    int blk = blockIdx.x;
    if (blk < 256) {
        int t = blk * 256 + threadIdx.x;      // 0..65535
        int lane = t & 63;
        int kt = (t >> 6) & 7;
        int nt = (t >> 9) & 3;
        int s  = (t >> 11) & 7;
        int e  = (t >> 14) & 3;
        int kbase = kt * 16 + ((lane >> 5) << 3);
        int n = nt * 32 + (lane & 31);
        const float* src = w + (size_t)e * W_STRIDE + (size_t)s * (U * V) + n;
        float sc = (s >= 4) ? 0.5f : 1.0f;
        __attribute__((aligned(16))) unsigned short o[8];
#pragma unroll
        for (int j = 0; j < 8; j++) o[j] = f2bf(src[(size_t)(kbase + j) * V] * sc);
        *(u32x4*)(wshuf + (size_t)t * 8) = *(const u32x4*)o;
    } else {
        __shared__ int lc[4];
        if (threadIdx.x < 4) lc[threadIdx.x] = 0;
        __syncthreads();
        int b = (blk - 256) * 256 + threadIdx.x;   // < 32768
        atomicAdd(&lc[wid[b]], 1);
        __syncthreads();
        if (threadIdx.x < 4) atomicAdd(&counts[threadIdx.x], lc[threadIdx.x]);
    }
}

// ---------------------------------------------------------------------------
// scatter: counting-sort row ids by expert into perm (order within expert
// arbitrary). Per-block LDS ranks + one global atomic per (block, expert).
// ---------------------------------------------------------------------------
__global__ void scatter_kernel(const int* __restrict__ wid, const int* __restrict__ counts,
                               int* __restrict__ cursors, int* __restrict__ perm) {
    __shared__ int lcnt[4], lbase[4];
    int tid = threadIdx.x;
    if (tid < 4) lcnt[tid] = 0;
    __syncthreads();
    int b = blockIdx.x * 256 + tid;   // < 32768
    int e = wid[b];
    int r = atomicAdd(&lcnt[e], 1);
    __syncthreads();
    if (tid < 4) lbase[tid] = atomicAdd(&cursors[tid], lcnt[tid]);
    __syncthreads();
    int off = 0;
#pragma unroll
    for (int i = 0; i < 4; i++)
        if (i < e) off += counts[i];
    perm[off + lbase[e] + r] = b;
}

// ---------------------------------------------------------------------------
// gemm: block = (expert e, tile of 64 sorted rows) x full 512 out cols.
// 8 waves: wave w computes out cols [w*64, w*64+64) for all 64 rows.
//   out block k = w>>1; K = 256 = x-block k (seg k) ++ x-block (k+3)&3 (seg +4).
// X staged to LDS as bf16, 64 rows x 512 cols, XOR pack swizzle:
//   element (r,c) at shorts offset r*512 + (((c>>3) ^ (r&7))<<3) + (c&7)
//   -> A-fragment ds_read_b128 hits every bank evenly.
// ---------------------------------------------------------------------------
__global__ __launch_bounds__(512) void gemm_kernel(
        const float* __restrict__ x, const unsigned short* __restrict__ wshuf,
        const int* __restrict__ counts, const int* __restrict__ perm,
        float* __restrict__ out) {
    int e = blockIdx.y;
    int tile = blockIdx.x;
    int c0 = counts[0], c1 = counts[1], c2 = counts[2], c3 = counts[3];
    int cnt = (e == 0) ? c0 : (e == 1) ? c1 : (e == 2) ? c2 : c3;
    int start = 0;
    if (e > 0) start += c0;
    if (e > 1) start += c1;
    if (e > 2) start += c2;
    if (tile * 64 >= cnt) return;
    int rows = cnt - tile * 64;
    if (rows > 64) rows = 64;
    int tstart = start + tile * 64;

    __shared__ unsigned short lds[64 * 512];   // 64 KB

    int t = threadIdx.x;

    // ---- stage X tile (gather via perm), fp32 -> bf16 ----
    {
        int r = t >> 3;           // 0..63
        int g = t & 7;
        bool valid = (r < rows);
        int row_g = valid ? perm[tstart + r] : 0;
        const float* xr = x + (size_t)row_g * IN_STRIDE;
#pragma unroll
        for (int i = 0; i < 16; i++) {
            int c = g * 4 + i * 32;
            float4 v = valid ? *(const float4*)(xr + c) : make_float4(0.f, 0.f, 0.f, 0.f);
            __attribute__((aligned(8))) unsigned short h[4];
            h[0] = f2bf(v.x); h[1] = f2bf(v.y); h[2] = f2bf(v.z); h[3] = f2bf(v.w);
            int off = r * 512 + ((((c >> 3) ^ (r & 7))) << 3) + (c & 7);
            *(u32x2*)(lds + off) = *(const u32x2*)h;
        }
    }
    __syncthreads();

    int w = t >> 6;          // wave 0..7
    int lane = t & 63;
    int kout = w >> 1;       // out block 0..3
    int nhalf = w & 1;       // which 64-col half of the block

    f32x16 acc00 = {}, acc01 = {}, acc10 = {}, acc11 = {};

    int xb[2]; int sg[2];
    xb[0] = kout;            sg[0] = kout;
    xb[1] = (kout + 3) & 3;  sg[1] = xb[1] + 4;

    const int m0 = lane & 31;
    const int khalf = (lane >> 5) << 3;
    const int rowswz = (m0 & 7);

#pragma unroll
    for (int c = 0; c < 2; c++) {
        int colbase = xb[c] * 128;
        const unsigned short* wseg =
            wshuf + (((size_t)(e * 8 + sg[c]) * 4 + nhalf * 2) * 8) * 64 * 8;
#pragma unroll
        for (int kt = 0; kt < 8; kt++) {
            int kabs = colbase + kt * 16 + khalf;
            int packoff = (((kabs >> 3) ^ rowswz) << 3);
            bf16x8 a0 = __builtin_bit_cast(bf16x8, *(const u32x4*)(lds + m0 * 512 + packoff));
            bf16x8 a1 = __builtin_bit_cast(bf16x8, *(const u32x4*)(lds + (m0 + 32) * 512 + packoff));
            bf16x8 b0 = __builtin_bit_cast(bf16x8, *(const u32x4*)(wseg + ((size_t)(kt) * 64 + lane) * 8));
            bf16x8 b1 = __builtin_bit_cast(bf16x8, *(const u32x4*)(wseg + ((size_t)(8 + kt) * 64 + lane) * 8));
            acc00 = __builtin_amdgcn_mfma_f32_32x32x16_bf16(a0, b0, acc00, 0, 0, 0);
            acc01 = __builtin_amdgcn_mfma_f32_32x32x16_bf16(a0, b1, acc01, 0, 0, 0);
            acc10 = __builtin_amdgcn_mfma_f32_32x32x16_bf16(a1, b0, acc10, 0, 0, 0);
            acc11 = __builtin_amdgcn_mfma_f32_32x32x16_bf16(a1, b1, acc11, 0, 0, 0);
        }
    }

    // ---- epilogue: C/D layout col=lane&31, row=(reg&3)+8*(reg>>2)+4*(lane>>5)
    int colb = kout * 128 + nhalf * 64 + (lane & 31);
    int rh = (lane >> 5) << 2;
#pragma unroll
    for (int q = 0; q < 4; q++) {
#pragma unroll
        for (int d = 0; d < 4; d++) {
            int reg = q * 4 + d;
            int rl0 = d + 8 * q + rh;          // rows 0..31 tile
            if (rl0 < rows) {
                int rg = perm[tstart + rl0];
                out[(size_t)rg * OUT_STRIDE + colb]      = acc00[reg];
                out[(size_t)rg * OUT_STRIDE + colb + 32] = acc01[reg];
            }
            int rl1 = rl0 + 32;                // rows 32..63 tile
            if (rl1 < rows) {
                int rg = perm[tstart + rl1];
                out[(size_t)rg * OUT_STRIDE + colb]      = acc10[reg];
                out[(size_t)rg * OUT_STRIDE + colb + 32] = acc11[reg];
            }
        }
    }
}

extern "C" void kernel_launch(void* const* d_in, const int* in_sizes, int n_in,
                              void* d_out, int out_size, void* d_ws, size_t ws_size,
                              hipStream_t stream) {
    const float* x = (const float*)d_in[0];
    const float* w = (const float*)d_in[1];
    const int* wid = (const int*)d_in[2];
    float* out = (float*)d_out;

    char* ws = (char*)d_ws;
    unsigned short* wshuf = (unsigned short*)(ws + WS_WSHUF);
    int* perm = (int*)(ws + WS_PERM);
    int* counts = (int*)(ws + WS_COUNTS);
    int* cursors = (int*)(ws + WS_CURS);

    // zero counts + cursors (32 bytes)
    hipMemsetAsync(counts, 0, 32, stream);
    prep_kernel<<<384, 256, 0, stream>>>(w, wid, wshuf, counts);
    scatter_kernel<<<128, 256, 0, stream>>>(wid, counts, cursors, perm);
    gemm_kernel<<<dim3(512, 4), 512, 0, stream>>>(x, wshuf, counts, perm, out);
}

// Round 2
// 136.168 us; speedup vs baseline: 1.1133x; 1.1133x over previous
//
#include <hip/hip_runtime.h>
#include <stdint.h>

#define U 128
#define V 128
#define IN_STRIDE 512
#define OUT_STRIDE 512
#define W_STRIDE (8 * U * V) /* 131072 floats per expert */
#define NB 32768

// Workspace layout (bytes)
#define WS_WSHUF 0                          // 524288 ushorts (1 MB) shuffled bf16 weights
#define WS_PERM  (1 << 20)                  // int[4*32768] padded per-expert regions (512 KB)
#define WS_CURS  ((1 << 20) + (1 << 19))    // int[4] cursors (= final per-expert counts)

typedef __bf16 bf16x8 __attribute__((ext_vector_type(8)));
typedef float f32x16 __attribute__((ext_vector_type(16)));
typedef unsigned int u32x4 __attribute__((ext_vector_type(4)));
typedef unsigned int u32x2 __attribute__((ext_vector_type(2)));

static __device__ __forceinline__ unsigned short f2bf(float f) {
    unsigned int u = __builtin_bit_cast(unsigned int, f);
    u += 0x7FFFu + ((u >> 16) & 1u);   // round-to-nearest-even
    return (unsigned short)(u >> 16);
}

// ---------------------------------------------------------------------------
// fused prep:
//  blocks [0,256): shuffle weights fp32 -> bf16 in MFMA B-fragment layout
//   flat short index = ((((e*8+s)*4+nt)*8+kt)*64+lane)*8 + j
//   element = W[e][s][k = kt*16+(lane>>5)*8+j][n = nt*32+(lane&31)], segs 4..7 ×0.5
//  blocks [256,384): counting-scatter row ids into padded per-expert perm
//   regions (perm[e*NB + pos]); cursors end up holding per-expert counts.
// ---------------------------------------------------------------------------
__global__ void prep_kernel(const float* __restrict__ w, const int* __restrict__ wid,
                            unsigned short* __restrict__ wshuf, int* __restrict__ cursors,
                            int* __restrict__ perm) {
    int blk = blockIdx.x;
    if (blk < 256) {
        int t = blk * 256 + threadIdx.x;      // 0..65535
        int lane = t & 63;
        int kt = (t >> 6) & 7;
        int nt = (t >> 9) & 3;
        int s  = (t >> 11) & 7;
        int e  = (t >> 14) & 3;
        int kbase = kt * 16 + ((lane >> 5) << 3);
        int n = nt * 32 + (lane & 31);
        const float* src = w + (size_t)e * W_STRIDE + (size_t)s * (U * V) + n;
        float sc = (s >= 4) ? 0.5f : 1.0f;
        __attribute__((aligned(16))) unsigned short o[8];
#pragma unroll
        for (int j = 0; j < 8; j++) o[j] = f2bf(src[(size_t)(kbase + j) * V] * sc);
        *(u32x4*)(wshuf + (size_t)t * 8) = *(const u32x4*)o;
    } else {
        __shared__ int lcnt[4], lbase[4];
        int tid = threadIdx.x;
        if (tid < 4) lcnt[tid] = 0;
        __syncthreads();
        int b = (blk - 256) * 256 + tid;   // < 32768
        int e = wid[b];
        int r = atomicAdd(&lcnt[e], 1);
        __syncthreads();
        if (tid < 4) lbase[tid] = atomicAdd(&cursors[tid], lcnt[tid]);
        __syncthreads();
        perm[e * NB + lbase[e] + r] = b;
    }
}

// ---------------------------------------------------------------------------
// gemm: block = (expert e, tile of 32 sorted rows) x full 512 out cols.
// 8 waves: wave w -> out block k = w>>1, 64-col half = w&1; rows 0..31.
//   K = 256 = x-block k (seg k) ++ x-block (k+3)&3 (seg +4, pre-scaled 0.5).
// X staged to LDS bf16, 32 rows x 512 cols, XOR pack swizzle:
//   (r,c) at shorts offset r*512 + (((c>>3) ^ (r&7))<<3) + (c&7)
// 32 KB LDS -> 4 blocks/CU, 32 waves/CU.
// ---------------------------------------------------------------------------
__global__ __launch_bounds__(512) void gemm_kernel(
        const float* __restrict__ x, const unsigned short* __restrict__ wshuf,
        const int* __restrict__ cursors, const int* __restrict__ perm,
        float* __restrict__ out) {
    int c4_0 = cursors[0], c4_1 = cursors[1], c4_2 = cursors[2], c4_3 = cursors[3];
    int cnts[4] = {c4_0, c4_1, c4_2, c4_3};
    int g = blockIdx.x;
    int e = -1, tile = 0, acc = 0;
#pragma unroll
    for (int i = 0; i < 4; i++) {
        int te = (cnts[i] + 31) >> 5;
        if (e < 0 && g < acc + te) { e = i; tile = g - acc; }
        acc += te;
    }
    if (e < 0) return;
    int cnt = cnts[e];
    int rows = cnt - tile * 32;
    if (rows > 32) rows = 32;
    int tbase = e * NB + tile * 32;

    __shared__ unsigned short lds[32 * 512];   // 32 KB
    __shared__ int s_perm[32];

    int t = threadIdx.x;

    // ---- stage X tile (gather via perm), fp32 -> bf16, swizzled ----
    {
        int r = t >> 4;           // 0..31
        int gg = t & 15;
        bool valid = (r < rows);
        int row_g = valid ? perm[tbase + r] : 0;
        if (gg == 0) s_perm[r] = row_g;
        const float* xr = x + (size_t)row_g * IN_STRIDE;
#pragma unroll
        for (int i = 0; i < 8; i++) {
            int c = gg * 4 + i * 64;
            float4 v = valid ? *(const float4*)(xr + c) : make_float4(0.f, 0.f, 0.f, 0.f);
            __attribute__((aligned(8))) unsigned short h[4];
            h[0] = f2bf(v.x); h[1] = f2bf(v.y); h[2] = f2bf(v.z); h[3] = f2bf(v.w);
            int off = r * 512 + ((((c >> 3) ^ (r & 7))) << 3) + (c & 7);
            *(u32x2*)(lds + off) = *(const u32x2*)h;
        }
    }
    __syncthreads();

    int w = t >> 6;          // wave 0..7
    int lane = t & 63;
    int kout = w >> 1;       // out block 0..3
    int nhalf = w & 1;       // which 64-col half of the block

    f32x16 acc0 = {}, acc1 = {};

    int xb[2]; int sg[2];
    xb[0] = kout;            sg[0] = kout;
    xb[1] = (kout + 3) & 3;  sg[1] = xb[1] + 4;

    const int m0 = lane & 31;
    const int khalf = (lane >> 5) << 3;
    const int rowswz = (m0 & 7);

#pragma unroll
    for (int c = 0; c < 2; c++) {
        int colbase = xb[c] * 128;
        const unsigned short* wseg =
            wshuf + (((size_t)(e * 8 + sg[c]) * 4 + nhalf * 2) * 8) * 64 * 8;
#pragma unroll
        for (int kt = 0; kt < 8; kt++) {
            int kabs = colbase + kt * 16 + khalf;
            int packoff = (((kabs >> 3) ^ rowswz) << 3);
            bf16x8 a0 = __builtin_bit_cast(bf16x8, *(const u32x4*)(lds + m0 * 512 + packoff));
            bf16x8 b0 = __builtin_bit_cast(bf16x8, *(const u32x4*)(wseg + ((size_t)(kt) * 64 + lane) * 8));
            bf16x8 b1 = __builtin_bit_cast(bf16x8, *(const u32x4*)(wseg + ((size_t)(8 + kt) * 64 + lane) * 8));
            acc0 = __builtin_amdgcn_mfma_f32_32x32x16_bf16(a0, b0, acc0, 0, 0, 0);
            acc1 = __builtin_amdgcn_mfma_f32_32x32x16_bf16(a0, b1, acc1, 0, 0, 0);
        }
    }

    // ---- epilogue: C/D layout col=lane&31, row=(reg&3)+8*(reg>>2)+4*(lane>>5)
    int colb = kout * 128 + nhalf * 64 + (lane & 31);
    int rh = (lane >> 5) << 2;
#pragma unroll
    for (int q = 0; q < 4; q++) {
#pragma unroll
        for (int d = 0; d < 4; d++) {
            int reg = q * 4 + d;
            int rl = d + 8 * q + rh;
            if (rl < rows) {
                int rg = s_perm[rl];
                out[(size_t)rg * OUT_STRIDE + colb]      = acc0[reg];
                out[(size_t)rg * OUT_STRIDE + colb + 32] = acc1[reg];
            }
        }
    }
}

extern "C" void kernel_launch(void* const* d_in, const int* in_sizes, int n_in,
                              void* d_out, int out_size, void* d_ws, size_t ws_size,
                              hipStream_t stream) {
    const float* x = (const float*)d_in[0];
    const float* w = (const float*)d_in[1];
    const int* wid = (const int*)d_in[2];
    float* out = (float*)d_out;

    char* ws = (char*)d_ws;
    unsigned short* wshuf = (unsigned short*)(ws + WS_WSHUF);
    int* perm = (int*)(ws + WS_PERM);
    int* cursors = (int*)(ws + WS_CURS);

    hipMemsetAsync(cursors, 0, 16, stream);
    prep_kernel<<<384, 256, 0, stream>>>(w, wid, wshuf, cursors, perm);
    // max tiles = sum ceil(cnt_e/32) <= 1024 + 3
    gemm_kernel<<<1027, 512, 0, stream>>>(x, wshuf, cursors, perm, out);
}

// Round 3
// 134.759 us; speedup vs baseline: 1.1250x; 1.0105x over previous
//
#include <hip/hip_runtime.h>
#include <stdint.h>

#define U 128
#define V 128
#define IN_STRIDE 512
#define OUT_STRIDE 512
#define W_STRIDE (8 * U * V) /* 131072 floats per expert */
#define NB 32768

// Workspace layout (bytes)
#define WS_WSHUF 0                          // 524288 ushorts (1 MB) shuffled bf16 weights
#define WS_PERM  (1 << 20)                  // int[4*32768] padded per-expert regions (512 KB)
#define WS_CURS  ((1 << 20) + (1 << 19))    // int[4] cursors (= final per-expert counts)

typedef __bf16 bf16x8 __attribute__((ext_vector_type(8)));
typedef float f32x16 __attribute__((ext_vector_type(16)));
typedef unsigned int u32x4 __attribute__((ext_vector_type(4)));
typedef unsigned int u32x2 __attribute__((ext_vector_type(2)));

static __device__ __forceinline__ unsigned short f2bf(float f) {
    unsigned int u = __builtin_bit_cast(unsigned int, f);
    u += 0x7FFFu + ((u >> 16) & 1u);   // round-to-nearest-even
    return (unsigned short)(u >> 16);
}

// ---------------------------------------------------------------------------
// fused prep (unchanged from R2):
//  blocks [0,256): weights fp32 -> bf16 in MFMA B-fragment layout
//   flat short index = ((((e*8+s)*4+nt)*8+kt)*64+lane)*8 + j
//   element = W[e][s][k = kt*16+(lane>>5)*8+j][n = nt*32+(lane&31)], segs 4..7 ×0.5
//  blocks [256,384): counting-scatter row ids into padded per-expert perm
//   regions (perm[e*NB + pos]); cursors end up holding per-expert counts.
// ---------------------------------------------------------------------------
__global__ void prep_kernel(const float* __restrict__ w, const int* __restrict__ wid,
                            unsigned short* __restrict__ wshuf, int* __restrict__ cursors,
                            int* __restrict__ perm) {
    int blk = blockIdx.x;
    if (blk < 256) {
        int t = blk * 256 + threadIdx.x;      // 0..65535
        int lane = t & 63;
        int kt = (t >> 6) & 7;
        int nt = (t >> 9) & 3;
        int s  = (t >> 11) & 7;
        int e  = (t >> 14) & 3;
        int kbase = kt * 16 + ((lane >> 5) << 3);
        int n = nt * 32 + (lane & 31);
        const float* src = w + (size_t)e * W_STRIDE + (size_t)s * (U * V) + n;
        float sc = (s >= 4) ? 0.5f : 1.0f;
        __attribute__((aligned(16))) unsigned short o[8];
#pragma unroll
        for (int j = 0; j < 8; j++) o[j] = f2bf(src[(size_t)(kbase + j) * V] * sc);
        *(u32x4*)(wshuf + (size_t)t * 8) = *(const u32x4*)o;
    } else {
        __shared__ int lcnt[4], lbase[4];
        int tid = threadIdx.x;
        if (tid < 4) lcnt[tid] = 0;
        __syncthreads();
        int b = (blk - 256) * 256 + tid;   // < 32768
        int e = wid[b];
        int r = atomicAdd(&lcnt[e], 1);
        __syncthreads();
        if (tid < 4) lbase[tid] = atomicAdd(&cursors[tid], lcnt[tid]);
        __syncthreads();
        perm[e * NB + lbase[e] + r] = b;
    }
}

// ---------------------------------------------------------------------------
// gemm R3: pipelined tile chains.
// grid = 512 blocks (2/CU at 64 KB LDS), block = 512 thr = 8 waves.
// Block b processes tiles g = b, b+512, ... (~2 tiles). Per iteration:
//   A: convert prefetched regs -> lds[buf] (XOR-swizzled), ONE barrier
//   B: issue global prefetch of tile g+grid into regs (in flight through C/D)
//   C: 32x32x16 MFMA compute (K=256: seg k ++ seg (k+3)&3 +4 prescaled 0.5)
//   D: scattered epilogue stores (drain overlaps next iter)
// Double LDS buffer -> single barrier/iter; stores/loads stay in flight.
// ---------------------------------------------------------------------------
__global__ __launch_bounds__(512) void gemm_kernel(
        const float* __restrict__ x, const unsigned short* __restrict__ wshuf,
        const int* __restrict__ cursors, const int* __restrict__ perm,
        float* __restrict__ out) {
    const int c0 = cursors[0], c1 = cursors[1], c2 = cursors[2], c3 = cursors[3];
    const int te0 = (c0 + 31) >> 5, te1 = (c1 + 31) >> 5,
              te2 = (c2 + 31) >> 5, te3 = (c3 + 31) >> 5;
    const int ntot = te0 + te1 + te2 + te3;

    __shared__ unsigned short lds[2][32 * 512];   // 64 KB
    __shared__ int s_perm[2][32];

    const int t = threadIdx.x;
    const int r = t >> 4;        // staging row 0..31
    const int gg = t & 15;       // staging col group

    const int w = t >> 6, lane = t & 63;
    const int kout = w >> 1, nhalf = w & 1;
    const int m0 = lane & 31;
    const int khalf = (lane >> 5) << 3;
    const int rowswz = m0 & 7;
    const int xb0 = kout, sg0 = kout;
    const int xb1 = (kout + 3) & 3, sg1 = xb1 + 4;
    const int colb = kout * 128 + nhalf * 64 + m0;
    const int rh = (lane >> 5) << 2;

    // tile mapping: g -> (expert, rows, perm base)
    auto map = [&](int g, int& e, int& rows, int& tbase) {
        int cs[4] = {c0, c1, c2, c3};
        int tes[4] = {te0, te1, te2, te3};
        int acc = 0; e = -1; rows = 0; tbase = 0;
#pragma unroll
        for (int i = 0; i < 4; i++) {
            if (e < 0 && g < acc + tes[i]) {
                e = i;
                int tile = g - acc;
                rows = cs[i] - tile * 32;
                if (rows > 32) rows = 32;
                tbase = i * NB + tile * 32;
            }
            acc += tes[i];
        }
    };

    int g = blockIdx.x;
    if (g >= ntot) return;
    int e_c, rows_c, tb_c;
    map(g, e_c, rows_c, tb_c);

    // prologue prefetch of first tile
    float4 pf[8];
    bool val = (r < rows_c);
    int rowg = val ? perm[tb_c + r] : 0;
    {
        const float* xr = x + (size_t)rowg * IN_STRIDE;
#pragma unroll
        for (int i = 0; i < 8; i++) {
            int c = gg * 4 + i * 64;
            if (val) pf[i] = *(const float4*)(xr + c);
        }
    }

    int buf = 0;
    while (true) {
        // ---- phase A: convert + ds_write into lds[buf] ----
        {
            unsigned short* L = lds[buf];
#pragma unroll
            for (int i = 0; i < 8; i++) {
                int c = gg * 4 + i * 64;
                float4 v = val ? pf[i] : make_float4(0.f, 0.f, 0.f, 0.f);
                __attribute__((aligned(8))) unsigned short h[4];
                h[0] = f2bf(v.x); h[1] = f2bf(v.y); h[2] = f2bf(v.z); h[3] = f2bf(v.w);
                int off = r * 512 + ((((c >> 3) ^ (r & 7))) << 3) + (c & 7);
                *(u32x2*)(L + off) = *(const u32x2*)h;
            }
            if (gg == 0) s_perm[buf][r] = rowg;
        }
        __syncthreads();   // the ONLY barrier per tile

        // ---- phase B: prefetch next tile into regs (stays in flight) ----
        int gn = g + gridDim.x;
        int e_n = -1, rows_n = 0, tb_n = 0;
        if (gn < ntot) {
            map(gn, e_n, rows_n, tb_n);
            bool vn = (r < rows_n);
            int rn = vn ? perm[tb_n + r] : 0;
            const float* xr = x + (size_t)rn * IN_STRIDE;
#pragma unroll
            for (int i = 0; i < 8; i++) {
                int c = gg * 4 + i * 64;
                if (vn) pf[i] = *(const float4*)(xr + c);
            }
            rowg = rn; val = vn;
        }

        // ---- phase C: compute ----
        const unsigned short* L = lds[buf];
        f32x16 acc0 = {}, acc1 = {};
        {
            int xbs[2] = {xb0, xb1};
            int sgs[2] = {sg0, sg1};
#pragma unroll
            for (int c = 0; c < 2; c++) {
                int colbase = xbs[c] * 128;
                const unsigned short* wseg =
                    wshuf + (((size_t)(e_c * 8 + sgs[c]) * 4 + nhalf * 2) * 8) * 64 * 8;
#pragma unroll
                for (int kt = 0; kt < 8; kt++) {
                    int kabs = colbase + kt * 16 + khalf;
                    int packoff = (((kabs >> 3) ^ rowswz) << 3);
                    bf16x8 a0 = __builtin_bit_cast(bf16x8, *(const u32x4*)(L + m0 * 512 + packoff));
                    bf16x8 b0 = __builtin_bit_cast(bf16x8, *(const u32x4*)(wseg + ((size_t)(kt) * 64 + lane) * 8));
                    bf16x8 b1 = __builtin_bit_cast(bf16x8, *(const u32x4*)(wseg + ((size_t)(8 + kt) * 64 + lane) * 8));
                    acc0 = __builtin_amdgcn_mfma_f32_32x32x16_bf16(a0, b0, acc0, 0, 0, 0);
                    acc1 = __builtin_amdgcn_mfma_f32_32x32x16_bf16(a0, b1, acc1, 0, 0, 0);
                }
            }
        }

        // ---- phase D: epilogue stores (C/D: col=lane&31, row=(reg&3)+8*(reg>>2)+4*(lane>>5))
#pragma unroll
        for (int q = 0; q < 4; q++) {
#pragma unroll
            for (int d = 0; d < 4; d++) {
                int reg = q * 4 + d;
                int rl = d + 8 * q + rh;
                if (rl < rows_c) {
                    int rg = s_perm[buf][rl];
                    out[(size_t)rg * OUT_STRIDE + colb]      = acc0[reg];
                    out[(size_t)rg * OUT_STRIDE + colb + 32] = acc1[reg];
                }
            }
        }

        if (e_n < 0) break;
        e_c = e_n; rows_c = rows_n; tb_c = tb_n; g = gn; buf ^= 1;
    }
}

extern "C" void kernel_launch(void* const* d_in, const int* in_sizes, int n_in,
                              void* d_out, int out_size, void* d_ws, size_t ws_size,
                              hipStream_t stream) {
    const float* x = (const float*)d_in[0];
    const float* w = (const float*)d_in[1];
    const int* wid = (const int*)d_in[2];
    float* out = (float*)d_out;

    char* ws = (char*)d_ws;
    unsigned short* wshuf = (unsigned short*)(ws + WS_WSHUF);
    int* perm = (int*)(ws + WS_PERM);
    int* cursors = (int*)(ws + WS_CURS);

    hipMemsetAsync(cursors, 0, 16, stream);
    prep_kernel<<<384, 256, 0, stream>>>(w, wid, wshuf, cursors, perm);
    // 2 blocks/CU resident; each block chains ~2 tiles (ntot <= 1027)
    gemm_kernel<<<512, 512, 0, stream>>>(x, wshuf, cursors, perm, out);
}

// Round 4
// 134.638 us; speedup vs baseline: 1.1260x; 1.0009x over previous
//
#include <hip/hip_runtime.h>
#include <stdint.h>

#define U 128
#define V 128
#define IN_STRIDE 512
#define OUT_STRIDE 512
#define W_STRIDE (8 * U * V) /* 131072 floats per expert */
#define NB 32768

// Workspace layout (bytes)
#define WS_WSHUF 0   // 524288 ushorts (1 MB) shuffled bf16 weights

typedef __bf16 bf16x8 __attribute__((ext_vector_type(8)));
typedef float f32x16 __attribute__((ext_vector_type(16)));
typedef unsigned int u32x4 __attribute__((ext_vector_type(4)));
typedef unsigned int u32x2 __attribute__((ext_vector_type(2)));

static __device__ __forceinline__ unsigned short f2bf(float f) {
    unsigned int u = __builtin_bit_cast(unsigned int, f);
    u += 0x7FFFu + ((u >> 16) & 1u);   // round-to-nearest-even
    return (unsigned short)(u >> 16);
}

// ---------------------------------------------------------------------------
// prep: weights fp32 -> bf16 in MFMA B-fragment layout (weight-only, no sort).
//   flat short index = ((((e*8+s)*4+nt)*8+kt)*64+lane)*8 + j
//   element = W[e][s][k = kt*16+(lane>>5)*8+j][n = nt*32+(lane&31)], segs 4..7 ×0.5
// ---------------------------------------------------------------------------
__global__ void prep_kernel(const float* __restrict__ w, unsigned short* __restrict__ wshuf) {
    int t = blockIdx.x * 256 + threadIdx.x;   // 0..65535
    int lane = t & 63;
    int kt = (t >> 6) & 7;
    int nt = (t >> 9) & 3;
    int s  = (t >> 11) & 7;
    int e  = (t >> 14) & 3;
    int kbase = kt * 16 + ((lane >> 5) << 3);
    int n = nt * 32 + (lane & 31);
    const float* src = w + (size_t)e * W_STRIDE + (size_t)s * (U * V) + n;
    float sc = (s >= 4) ? 0.5f : 1.0f;
    __attribute__((aligned(16))) unsigned short o[8];
#pragma unroll
    for (int j = 0; j < 8; j++) o[j] = f2bf(src[(size_t)(kbase + j) * V] * sc);
    *(u32x4*)(wshuf + (size_t)t * 8) = *(const u32x4*)o;
}

// ---------------------------------------------------------------------------
// gemm R4: no sort. Block = 64 CONSECUTIVE rows x full 512 cols (grid 512 exact).
// Expert handled by A-fragment masking: 4 passes over e; lane's A rows zeroed
// unless wid[row]==e. Rows map 1:1 to lanes in the 32x32x16 A layout
// (m = lane&31), so the mask is wave-resident: 4 v_and per fragment.
// 8 waves: wave w -> kout=w>>1 (out block), nhalf=w&1 (64-col half); each wave
// covers both 32-row halves (B fragments shared across halves -> B traffic
// stays at 1 MB/block).
// K=256 per kout: x-block kout (seg kout) ++ x-block (kout+3)&3 (seg +4, x0.5
// pre-folded). X staged once to LDS bf16 with XOR pack swizzle:
//   (r,c) at shorts offset r*512 + (((c>>3) ^ (r&7))<<3) + (c&7)
// LDS 64 KB -> 2 blocks/CU; __launch_bounds__(512,4) keeps VGPR <= 128.
// Loads and stores are fully sequential 128 KB streams per block.
// ---------------------------------------------------------------------------
__global__ __launch_bounds__(512, 4) void gemm_kernel(
        const float* __restrict__ x, const unsigned short* __restrict__ wshuf,
        const int* __restrict__ wid, float* __restrict__ out) {
    const int rowbase = blockIdx.x * 64;
    __shared__ unsigned short lds[64 * 512];   // 64 KB

    const int t = threadIdx.x;

    // ---- stage X tile (consecutive rows), fp32 -> bf16, swizzled ----
    {
        int r = t >> 3;            // 0..63
        int g = t & 7;
        const float* xr = x + (size_t)(rowbase + r) * IN_STRIDE;
        unsigned short* Lrow = lds + r * 512;
        int rs = r & 7;
#pragma unroll
        for (int i = 0; i < 16; i++) {
            int c = g * 4 + i * 32;
            float4 v = *(const float4*)(xr + c);
            __attribute__((aligned(8))) unsigned short h[4];
            h[0] = f2bf(v.x); h[1] = f2bf(v.y); h[2] = f2bf(v.z); h[3] = f2bf(v.w);
            int off = ((((c >> 3) ^ rs)) << 3) + (c & 7);
            *(u32x2*)(Lrow + off) = *(const u32x2*)h;
        }
    }

    const int w = t >> 6, lane = t & 63;
    const int kout = w >> 1, nhalf = w & 1;
    const int m0 = lane & 31;
    const int khalf3 = (lane >> 5);            // 0/1: k-offset/8 within k-tile
    const int rowswz = m0 & 7;

    // per-lane expert of the two rows this lane's A fragments represent
    const int e0 = wid[rowbase + m0];
    const int e1 = wid[rowbase + m0 + 32];

    __syncthreads();   // single barrier

    unsigned int msk0[4], msk1[4];
#pragma unroll
    for (int e = 0; e < 4; e++) {
        msk0[e] = (e0 == e) ? 0xFFFFFFFFu : 0u;
        msk1[e] = (e1 == e) ? 0xFFFFFFFFu : 0u;
    }

    f32x16 acc00 = {}, acc01 = {}, acc10 = {}, acc11 = {};

    const int xbs0 = kout, xbs1 = (kout + 3) & 3;
    const int sgs0 = kout, sgs1 = xbs1 + 4;
    int xbs[2] = {xbs0, xbs1};
    int sgs[2] = {sgs0, sgs1};

    const unsigned short* Lr0 = lds + m0 * 512;
    const unsigned short* Lr1 = lds + (m0 + 32) * 512;

#pragma unroll
    for (int c = 0; c < 2; c++) {
        int colbase3 = xbs[c] * 16;   // (xb*128)>>3
#pragma unroll
        for (int kt = 0; kt < 8; kt++) {
            int kabs3 = colbase3 + kt * 2 + khalf3;
            int packoff = ((kabs3 ^ rowswz) << 3);
            u32x4 a0u = *(const u32x4*)(Lr0 + packoff);
            u32x4 a1u = *(const u32x4*)(Lr1 + packoff);
#pragma unroll
            for (int e = 0; e < 4; e++) {
                const unsigned short* wseg =
                    wshuf + ((size_t)((e * 8 + sgs[c]) * 4 + nhalf * 2) * 8) * 512;
                bf16x8 b0 = __builtin_bit_cast(bf16x8, *(const u32x4*)(wseg + (size_t)kt * 512 + lane * 8));
                bf16x8 b1 = __builtin_bit_cast(bf16x8, *(const u32x4*)(wseg + (size_t)(8 + kt) * 512 + lane * 8));
                u32x4 mm0 = {msk0[e], msk0[e], msk0[e], msk0[e]};
                u32x4 mm1 = {msk1[e], msk1[e], msk1[e], msk1[e]};
                bf16x8 a0m = __builtin_bit_cast(bf16x8, a0u & mm0);
                bf16x8 a1m = __builtin_bit_cast(bf16x8, a1u & mm1);
                acc00 = __builtin_amdgcn_mfma_f32_32x32x16_bf16(a0m, b0, acc00, 0, 0, 0);
                acc01 = __builtin_amdgcn_mfma_f32_32x32x16_bf16(a0m, b1, acc01, 0, 0, 0);
                acc10 = __builtin_amdgcn_mfma_f32_32x32x16_bf16(a1m, b0, acc10, 0, 0, 0);
                acc11 = __builtin_amdgcn_mfma_f32_32x32x16_bf16(a1m, b1, acc11, 0, 0, 0);
            }
        }
    }

    // ---- epilogue: C/D layout col=lane&31, row=(reg&3)+8*(reg>>2)+4*(lane>>5)
    // rows are consecutive globals -> 128B segments, sequential across block.
    const int colb = kout * 128 + nhalf * 64 + m0;
    const int rh = (lane >> 5) << 2;
#pragma unroll
    for (int q = 0; q < 4; q++) {
#pragma unroll
        for (int d = 0; d < 4; d++) {
            int reg = q * 4 + d;
            int rl = d + 8 * q + rh;
            float* o0 = out + (size_t)(rowbase + rl) * OUT_STRIDE + colb;
            float* o1 = out + (size_t)(rowbase + rl + 32) * OUT_STRIDE + colb;
            o0[0]  = acc00[reg];
            o0[32] = acc01[reg];
            o1[0]  = acc10[reg];
            o1[32] = acc11[reg];
        }
    }
}

extern "C" void kernel_launch(void* const* d_in, const int* in_sizes, int n_in,
                              void* d_out, int out_size, void* d_ws, size_t ws_size,
                              hipStream_t stream) {
    const float* x = (const float*)d_in[0];
    const float* w = (const float*)d_in[1];
    const int* wid = (const int*)d_in[2];
    float* out = (float*)d_out;

    unsigned short* wshuf = (unsigned short*)((char*)d_ws + WS_WSHUF);

    prep_kernel<<<256, 256, 0, stream>>>(w, wshuf);
    gemm_kernel<<<512, 512, 0, stream>>>(x, wshuf, wid, out);
}